// Round 12
// baseline (25.959 us; speedup 1.0000x reference)
//
#include <hip/hip_runtime.h>

#define HH 128
#define WW 192
#define HW (HH * WW)
#define TS 196   // LDS tile row stride (floats): 196*4=784 bytes, 16B-aligned, 196%32=4 spreads banks

typedef float f32x4 __attribute__((ext_vector_type(4)));

__device__ __forceinline__ float relu(float v) { return fmaxf(v, 0.0f); }

// LDS weight layout (176 floats; every f32x4 row 16B-aligned):
// [0..7] w0x[o]  [8..15] w0y[o]  [16..23] b0[o]
// [24..87] w0t[ch][o] (8 rows of 8)  [88..151] w1t[i][o] (8 rows of 8)
// [152..159] w2[o]  [160..167] b1[o]  [168] b2

__global__ __launch_bounds__(256) void dmh_kernel(
    const float* __restrict__ mask_feats,   // (4,8,128,192)
    const float* __restrict__ params,       // (128,169)
    const float* __restrict__ locs,         // (128,2)
    const float* __restrict__ soi,          // (5,)
    const int*   __restrict__ im_inds,      // (128,)
    const int*   __restrict__ fpn_levels,   // (128,)
    const int*   __restrict__ stride_p,     // scalar (=8)
    float*       __restrict__ out)          // (128,1,256,384)
{
    const int tid = threadIdx.x;
    const int r0  = blockIdx.x * 16;  // source row-tile origin (full 192-col width)
    const int n   = blockIdx.y;       // instance

    __shared__ float sW[176];
    __shared__ float tile[17 * TS];   // src rows r0-1 .. r0+15 (row 0 clamped), 192 cols used

    // ---- issue weight load first ----
    float wv = 0.0f;
    if (tid < 169) wv = params[(size_t)n * 169 + tid];

    const int   stride = *stride_p;                 // 8
    const float half_s = 0.5f * (float)stride;      // 4.0
    const float locx = locs[2 * n + 0];
    const float locy = locs[2 * n + 1];
    const float inv  = 1.0f / soi[fpn_levels[n]];
    const float* fb  = mask_feats + (size_t)im_inds[n] * 8 * HW;

    // ---- unit 0 feat loads issued before the staging barrier ----
    // unit u (0..815): row = u/48 (0..16), colgrp = u%48; 4 contiguous px
    const int row0 = tid / 48;
    const int cg0  = tid - row0 * 48;
    const int srow0 = max(r0 - 1 + row0, 0);        // only top edge clamps
    const int col00 = cg0 * 4;
    const float* fp0 = fb + srow0 * WW + col00;
    f32x4 xv0[8];
    #pragma unroll
    for (int ch = 0; ch < 8; ++ch)
        xv0[ch] = *reinterpret_cast<const f32x4*>(fp0 + ch * HW);

    // ---- scatter weights (transposed) into LDS ----
    if (tid < 169) {
        int d;
        if (tid < 80)       { int o = tid / 10, r = tid - o * 10;
                              d = (r == 0) ? o : (r == 1) ? (8 + o) : (24 + (r - 2) * 8 + o); }
        else if (tid < 144) { int t = tid - 80, o = t >> 3, i = t & 7; d = 88 + i * 8 + o; }
        else if (tid < 152) d = 152 + (tid - 144);
        else if (tid < 160) d = 16 + (tid - 152);
        else if (tid < 168) d = 160 + (tid - 160);
        else                d = 168;
        sW[d] = wv;
    }
    __syncthreads();

    const f32x4* __restrict__ sW4 = reinterpret_cast<const f32x4*>(sW);

    // ---- per-unit MLP (4 contiguous px of one src row) ----
    auto compute_unit = [&](int row, int col0, int srow, const f32x4* xv) {
        const float rxd = -(float)stride * inv;
        float rx[4];
        rx[0] = (locx - (float)(col0 * stride) - half_s) * inv;
        rx[1] = rx[0] + rxd; rx[2] = rx[1] + rxd; rx[3] = rx[2] + rxd;
        const float ry = (locy - (float)(srow * stride) - half_s) * inv;

        f32x4 w0xL = sW4[0], w0xH = sW4[1];
        f32x4 w0yL = sW4[2], w0yH = sW4[3];
        f32x4 b0L  = sW4[4], b0H  = sW4[5];

        float h[8][4];
        #pragma unroll
        for (int o = 0; o < 8; ++o) {
            float wx = (o < 4) ? w0xL[o] : w0xH[o - 4];
            float wy = (o < 4) ? w0yL[o] : w0yH[o - 4];
            float b  = (o < 4) ? b0L[o]  : b0H[o - 4];
            float t  = fmaf(wy, ry, b);
            #pragma unroll
            for (int j = 0; j < 4; ++j) h[o][j] = fmaf(wx, rx[j], t);
        }
        #pragma unroll
        for (int ch = 0; ch < 8; ++ch) {
            f32x4 wL = sW4[6 + 2 * ch];
            f32x4 wH = sW4[7 + 2 * ch];
            #pragma unroll
            for (int o = 0; o < 8; ++o) {
                float w = (o < 4) ? wL[o] : wH[o - 4];
                #pragma unroll
                for (int j = 0; j < 4; ++j) h[o][j] = fmaf(w, xv[ch][j], h[o][j]);
            }
        }
        float a[8][4];
        {
            f32x4 b1L = sW4[40], b1H = sW4[41];
            #pragma unroll
            for (int o = 0; o < 8; ++o) {
                float b = (o < 4) ? b1L[o] : b1H[o - 4];
                #pragma unroll
                for (int j = 0; j < 4; ++j) a[o][j] = b;
            }
        }
        #pragma unroll
        for (int i = 0; i < 8; ++i) {
            f32x4 wL = sW4[22 + 2 * i];
            f32x4 wH = sW4[23 + 2 * i];
            float v[4];
            #pragma unroll
            for (int j = 0; j < 4; ++j) v[j] = relu(h[i][j]);
            #pragma unroll
            for (int o = 0; o < 8; ++o) {
                float w = (o < 4) ? wL[o] : wH[o - 4];
                #pragma unroll
                for (int j = 0; j < 4; ++j) a[o][j] = fmaf(w, v[j], a[o][j]);
            }
        }
        f32x4 w2L = sW4[38], w2H = sW4[39];
        const float b2v = sW[168];
        f32x4 lg = {b2v, b2v, b2v, b2v};
        #pragma unroll
        for (int o = 0; o < 8; ++o) {
            float w2 = (o < 4) ? w2L[o] : w2H[o - 4];
            #pragma unroll
            for (int j = 0; j < 4; ++j) lg[j] = fmaf(w2, relu(a[o][j]), lg[j]);
        }
        *reinterpret_cast<f32x4*>(&tile[row * TS + col0]) = lg;
    };

    auto do_unit = [&](int u) {
        int row = u / 48;
        int cg  = u - row * 48;
        int srow = max(r0 - 1 + row, 0);
        int col0 = cg * 4;
        const float* fp = fb + srow * WW + col0;
        f32x4 xv[8];
        #pragma unroll
        for (int ch = 0; ch < 8; ++ch)
            xv[ch] = *reinterpret_cast<const f32x4*>(fp + ch * HW);
        compute_unit(row, col0, srow, xv);
    };

    compute_unit(row0, col00, srow0, xv0);   // unit 0 (loads already in flight)
    do_unit(tid + 256);
    do_unit(tid + 512);
    if (tid < 48) do_unit(768 + tid);
    __syncthreads();

    // ---------- phase 2: x2 aligned upsample -> 32 full output rows ----------
    // out row y = 2*r0 + ro; needs tile rows lr = rb-r0+1, lr+fy (rb=(y-1)>>1)
    const int a8 = tid & 7;           // col-chunk lane
    const int ro = tid >> 3;          // 0..31
    const int y  = 2 * r0 + ro;
    const int iy = y - 1;
    const int rb = iy >> 1;           // arithmetic shift handles iy=-1
    const int fy = iy & 1;
    const float wy0 = fy ? 0.5f : 1.0f;
    const float wy1 = fy ? 0.5f : 0.0f;
    const int lr  = rb - r0 + 1;      // in [0,16]
    const int lr2 = lr + fy;          // in [0,16]
    const float* ta = &tile[lr  * TS];
    const float* tb = &tile[lr2 * TS];
    float* obr = out + ((size_t)n * 256 + y) * 384;

    #pragma unroll
    for (int q = 0; q < 12; ++q) {
        int f4 = q * 8 + a8;          // float4 index 0..95 along the row
        int m0 = 2 * f4 - 1;          // src col for out col 4*f4 (may be -1)
        int mc = max(m0, 0);
        float t0 = fmaf(wy1, tb[mc],     wy0 * ta[mc]);
        float t1 = fmaf(wy1, tb[m0 + 1], wy0 * ta[m0 + 1]);
        float t2 = fmaf(wy1, tb[m0 + 2], wy0 * ta[m0 + 2]);
        f32x4 o4;
        o4.x = 0.5f * (t0 + t1);
        o4.y = t1;
        o4.z = 0.5f * (t1 + t2);
        o4.w = t2;
        __builtin_nontemporal_store(o4, reinterpret_cast<f32x4*>(obr + 4 * f4));
    }
}

extern "C" void kernel_launch(void* const* d_in, const int* in_sizes, int n_in,
                              void* d_out, int out_size, void* d_ws, size_t ws_size,
                              hipStream_t stream) {
    const float* mask_feats = (const float*)d_in[0];
    const float* params     = (const float*)d_in[1];
    const float* locs       = (const float*)d_in[2];
    const float* soi        = (const float*)d_in[3];
    const int*   im_inds    = (const int*)d_in[4];
    const int*   fpn_levels = (const int*)d_in[5];
    const int*   stride_p   = (const int*)d_in[6];
    float* out = (float*)d_out;

    dim3 grid(HH / 16, 128);   // (8, 128) row-tiles x instances
    dim3 block(256);
    dmh_kernel<<<grid, block, 0, stream>>>(
        mask_feats, params, locs, soi, im_inds, fpn_levels, stride_p, out);
}